// Round 1
// baseline (80.290 us; speedup 1.0000x reference)
//
#include <hip/hip_runtime.h>

#define LSEQ 512
#define IN_CH 16
#define OUT_CH 16
#define HIDDEN 8
#define KSZ 5

// One block (1 wave of 64 threads) per (b,l) row.
// thread t: o = t&15 (output channel), jg = t>>4 (4-way split of the j band).
__global__ __launch_bounds__(64) void contconv_kernel(
    const float* __restrict__ times,      // (B, L)
    const float* __restrict__ feat,       // (B, L, IN_CH)
    const int*   __restrict__ lengths,    // (B,)
    const int*   __restrict__ true_ids,   // (B, L) 0/1
    const int*   __restrict__ sim_size_p, // (1,)
    const float* __restrict__ w1,         // (1, HIDDEN)
    const float* __restrict__ b1,         // (HIDDEN,)
    const float* __restrict__ w2,         // (HIDDEN, IN_CH*OUT_CH)
    const float* __restrict__ b2,         // (IN_CH*OUT_CH,)
    float*       __restrict__ out)        // (B, L, OUT_CH)
{
    const int bl = blockIdx.x;
    const int b  = bl >> 9;          // L = 512
    const int l  = bl & (LSEQ - 1);
    const int t  = threadIdx.x;
    const int o  = t & 15;
    const int jg = t >> 4;           // 0..3

    __shared__ float s_w2[HIDDEN * IN_CH * OUT_CH]; // 8*256 = 2048 floats (8 KB)
    __shared__ float s_b2[IN_CH * OUT_CH];          // 256 floats (1 KB)
    for (int k = t; k < HIDDEN * IN_CH * OUT_CH; k += 64) s_w2[k] = w2[k];
    for (int k = t; k < IN_CH * OUT_CH; k += 64)          s_b2[k] = b2[k];

    const int sim  = sim_size_p[0];
    const int band = (sim + 1) * KSZ;                 // 30
    const int len  = lengths[b];
    const bool rowvalid = (l <= (sim + 1) * (len - 1));

    float w1r[HIDDEN], b1r[HIDDEN];
#pragma unroll
    for (int h = 0; h < HIDDEN; ++h) { w1r[h] = w1[h]; b1r[h] = b1[h]; }

    __syncthreads();

    float acc = 0.0f;
    if (rowvalid) {
        const float tl = times[b * LSEQ + l];
        int jlo = l - band + 1;
        if (jlo < 0) jlo = 0;
        for (int j = jlo + jg; j <= l; j += 4) {
            if (true_ids[b * LSEQ + j] == 0) continue;
            const float dt = tl - times[b * LSEQ + j];

            float hv[HIDDEN];
#pragma unroll
            for (int h = 0; h < HIDDEN; ++h) {
                const float x = dt * w1r[h] + b1r[h];
                hv[h] = x > 0.0f ? x : 0.0f;
            }

            float q[HIDDEN];
#pragma unroll
            for (int h = 0; h < HIDDEN; ++h) q[h] = 0.0f;
            float fb = 0.0f;

            const float* fj = feat + (b * LSEQ + j) * IN_CH;
#pragma unroll
            for (int i = 0; i < IN_CH; ++i) {
                const float f = fj[i];
                fb += f * s_b2[i * OUT_CH + o];
#pragma unroll
                for (int h = 0; h < HIDDEN; ++h)
                    q[h] += f * s_w2[h * (IN_CH * OUT_CH) + i * OUT_CH + o];
            }

            float contrib = fb;
#pragma unroll
            for (int h = 0; h < HIDDEN; ++h) contrib += hv[h] * q[h];
            acc += contrib;
        }
    }

    // reduce the 4 j-groups: lanes with same o are t, t^16, t^32(, t^48)
    acc += __shfl_xor(acc, 16, 64);
    acc += __shfl_xor(acc, 32, 64);

    if (t < 16) out[(b * LSEQ + l) * OUT_CH + o] = acc;
}

extern "C" void kernel_launch(void* const* d_in, const int* in_sizes, int n_in,
                              void* d_out, int out_size, void* d_ws, size_t ws_size,
                              hipStream_t stream) {
    const float* times    = (const float*)d_in[0];
    const float* feat     = (const float*)d_in[1];
    const int*   lengths  = (const int*)  d_in[2];
    const int*   true_ids = (const int*)  d_in[3];
    const int*   sim      = (const int*)  d_in[4];
    const float* w1       = (const float*)d_in[5];
    const float* b1       = (const float*)d_in[6];
    const float* w2       = (const float*)d_in[7];
    const float* b2       = (const float*)d_in[8];
    float* out = (float*)d_out;

    const int BS = in_sizes[0] / LSEQ;  // 2
    contconv_kernel<<<BS * LSEQ, 64, 0, stream>>>(
        times, feat, lengths, true_ids, sim, w1, b1, w2, b2, out);
}

// Round 2
// 79.225 us; speedup vs baseline: 1.0135x; 1.0135x over previous
//
#include <hip/hip_runtime.h>

#define LSEQ 512
#define IN_CH 16
#define OUT_CH 16
#define HIDDEN 8
#define KSZ 5
#define PSTRIDE 12   // floats per (j,o) record: 8 G, 1 F, 3 pad (48 B, float4-aligned)

// ---------------- Phase 1 ----------------
// For every (b,j,o): G[h] = sum_i feat[b,j,i] * w2[h, i*16+o],  F = sum_i feat*b2[i*16+o],
// both multiplied by true_ids[b,j]. Written to P[(b*L+j)*16 + o][0..8].
// Block = 256 threads = 16 j-positions x 16 o. Grid = B*L/16 blocks.
__global__ __launch_bounds__(256) void phase1_kernel(
    const float* __restrict__ feat,      // (B, L, IN_CH)
    const int*   __restrict__ true_ids,  // (B, L)
    const float* __restrict__ w2,        // (HIDDEN, 256)
    const float* __restrict__ b2,        // (256,)
    float*       __restrict__ P)         // (B*L*16, PSTRIDE)
{
    const int t  = threadIdx.x;
    const int o  = t & 15;
    const int jl = t >> 4;                     // 0..15
    const int bj = blockIdx.x * 16 + jl;       // flat (b*L + j)

    // stage w2 transposed: s_w2t[o][i][h] (h contiguous -> b128 reads below)
    __shared__ float s_w2t[OUT_CH * IN_CH * HIDDEN];   // 2048 floats
    __shared__ float s_b2[IN_CH * OUT_CH];             // 256 floats
    for (int k = t; k < HIDDEN * IN_CH * OUT_CH; k += 256) {
        const int h = k >> 8, rem = k & 255, i = rem >> 4, oo = rem & 15;
        s_w2t[(oo * IN_CH + i) * HIDDEN + h] = w2[k];
    }
    s_b2[t] = b2[t];
    __syncthreads();

    // load feature vector (16 floats) as 4x float4
    const float4* f4 = (const float4*)(feat + bj * IN_CH);
    float f[IN_CH];
    {
        float4 a0 = f4[0], a1 = f4[1], a2 = f4[2], a3 = f4[3];
        f[0]=a0.x; f[1]=a0.y; f[2]=a0.z; f[3]=a0.w;
        f[4]=a1.x; f[5]=a1.y; f[6]=a1.z; f[7]=a1.w;
        f[8]=a2.x; f[9]=a2.y; f[10]=a2.z; f[11]=a2.w;
        f[12]=a3.x; f[13]=a3.y; f[14]=a3.z; f[15]=a3.w;
    }
    const float m = (true_ids[bj] != 0) ? 1.0f : 0.0f;

    float q[HIDDEN];
#pragma unroll
    for (int h = 0; h < HIDDEN; ++h) q[h] = 0.0f;
    float F = 0.0f;

#pragma unroll
    for (int i = 0; i < IN_CH; ++i) {
        const float* wrow = &s_w2t[(o * IN_CH + i) * HIDDEN];
        const float fi = f[i];
#pragma unroll
        for (int h = 0; h < HIDDEN; ++h) q[h] += fi * wrow[h];
        F += fi * s_b2[i * OUT_CH + o];
    }

    float4* dst = (float4*)(P + (bj * OUT_CH + o) * PSTRIDE);
    dst[0] = make_float4(q[0]*m, q[1]*m, q[2]*m, q[3]*m);
    dst[1] = make_float4(q[4]*m, q[5]*m, q[6]*m, q[7]*m);
    dst[2] = make_float4(F*m, 0.0f, 0.0f, 0.0f);
}

// ---------------- Phase 2 ----------------
// One wave per (b,l) row: thread t -> o = t&15, jg = t>>4 (4-way j split).
// out[b,l,o] = sum_{j in band} [ sum_h relu(dt*w1[h]+b1[h]) * G[b,j,h,o] + F[b,j,o] ]
__global__ __launch_bounds__(64) void phase2_kernel(
    const float* __restrict__ times,      // (B, L)
    const int*   __restrict__ lengths,    // (B,)
    const int*   __restrict__ sim_size_p, // (1,)
    const float* __restrict__ w1,         // (HIDDEN,)
    const float* __restrict__ b1,         // (HIDDEN,)
    const float* __restrict__ P,          // phase-1 output
    float*       __restrict__ out)        // (B, L, OUT_CH)
{
    const int bl = blockIdx.x;
    const int b  = bl >> 9;               // L = 512
    const int l  = bl & (LSEQ - 1);
    const int t  = threadIdx.x;
    const int o  = t & 15;
    const int jg = t >> 4;                // 0..3

    const int sim = sim_size_p[0];
    const int len = lengths[b];

    float acc = 0.0f;
    if (l <= (sim + 1) * (len - 1)) {
        float w1r[HIDDEN], b1r[HIDDEN];
#pragma unroll
        for (int h = 0; h < HIDDEN; ++h) { w1r[h] = w1[h]; b1r[h] = b1[h]; }

        const float tl = times[b * LSEQ + l];
        int jlo = l - (sim + 1) * KSZ + 1;
        if (jlo < 0) jlo = 0;

        for (int j = jlo + jg; j <= l; j += 4) {
            const float dt = tl - times[b * LSEQ + j];
            const float4* p4 = (const float4*)(P + ((b * LSEQ + j) * OUT_CH + o) * PSTRIDE);
            const float4 g0 = p4[0];
            const float4 g1 = p4[1];
            const float4 g2 = p4[2];

            acc += g2.x;  // bias (F) term, pre-masked
            acc += fmaxf(dt * w1r[0] + b1r[0], 0.0f) * g0.x;
            acc += fmaxf(dt * w1r[1] + b1r[1], 0.0f) * g0.y;
            acc += fmaxf(dt * w1r[2] + b1r[2], 0.0f) * g0.z;
            acc += fmaxf(dt * w1r[3] + b1r[3], 0.0f) * g0.w;
            acc += fmaxf(dt * w1r[4] + b1r[4], 0.0f) * g1.x;
            acc += fmaxf(dt * w1r[5] + b1r[5], 0.0f) * g1.y;
            acc += fmaxf(dt * w1r[6] + b1r[6], 0.0f) * g1.z;
            acc += fmaxf(dt * w1r[7] + b1r[7], 0.0f) * g1.w;
        }
    }

    // reduce the 4 j-groups (lanes t, t^16, t^32, t^48 share the same o)
    acc += __shfl_xor(acc, 16, 64);
    acc += __shfl_xor(acc, 32, 64);

    if (t < 16) out[(b * LSEQ + l) * OUT_CH + o] = acc;
}

extern "C" void kernel_launch(void* const* d_in, const int* in_sizes, int n_in,
                              void* d_out, int out_size, void* d_ws, size_t ws_size,
                              hipStream_t stream) {
    const float* times    = (const float*)d_in[0];
    const float* feat     = (const float*)d_in[1];
    const int*   lengths  = (const int*)  d_in[2];
    const int*   true_ids = (const int*)  d_in[3];
    const int*   sim      = (const int*)  d_in[4];
    const float* w1       = (const float*)d_in[5];
    const float* b1       = (const float*)d_in[6];
    const float* w2       = (const float*)d_in[7];
    const float* b2       = (const float*)d_in[8];
    float* out = (float*)d_out;
    float* P   = (float*)d_ws;   // (B*L*16) * PSTRIDE floats = 768 KB for B=2

    const int BS = in_sizes[0] / LSEQ;  // 2

    phase1_kernel<<<BS * LSEQ / 16, 256, 0, stream>>>(feat, true_ids, w2, b2, P);
    phase2_kernel<<<BS * LSEQ, 64, 0, stream>>>(times, lengths, sim, w1, b1, P, out);
}